// Round 3
// baseline (17997.731 us; speedup 1.0000x reference)
//
#include <hip/hip_runtime.h>
#include <math.h>

// Problem dims (fixed by reference)
#define TT 128
#define BB 64
#define II 1024
#define HH 1024
#define KK 8
#define G4 4096   // 4*H
#define TI 128    // reduction col tile

// Workspace layout (float offsets). Total ~2.36 MB — safe for any ws_size.
#define WS_CW   0                       // [T][K] softmax'd coefs
#define WS_BIAS (WS_CW + TT*KK)         // [T][4H] mixed bias
#define WS_C    (WS_BIAS + TT*G4)       // [B][H] cell state

__global__ __launch_bounds__(256) void softmax_bias_kernel(
    const float* __restrict__ coef,
    const float* __restrict__ b_ih,
    const float* __restrict__ b_hh,
    float* __restrict__ ws)
{
    int t = blockIdx.x;
    float c[KK];
    float m = -1e30f;
    #pragma unroll
    for (int k = 0; k < KK; ++k) { c[k] = coef[t*KK + k]; m = fmaxf(m, c[k]); }
    float s = 0.f;
    #pragma unroll
    for (int k = 0; k < KK; ++k) { c[k] = expf(c[k] - m); s += c[k]; }
    float inv = 1.f / s;
    #pragma unroll
    for (int k = 0; k < KK; ++k) c[k] *= inv;
    if (threadIdx.x < KK) ws[WS_CW + t*KK + threadIdx.x] = c[threadIdx.x];
    for (int g = threadIdx.x; g < G4; g += blockDim.x) {
        float acc = 0.f;
        #pragma unroll
        for (int k = 0; k < KK; ++k)
            acc += c[k] * (b_ih[k*G4 + g] + b_hh[k*G4 + g]);
        ws[WS_BIAS + t*G4 + g] = acc;
    }
}

// One fused LSTM step. Grid: H/4 = 256 blocks (each block: 4 j-cols x ALL 4
// gates x all 64 batch rows, then the pointwise LSTM update for its 4 cols).
__global__ __launch_bounds__(256) void step_kernel(
    const float* __restrict__ x_t,     // [B, I]
    const float* __restrict__ hprev,   // [B, H]
    const float* __restrict__ cprev,   // [B, H]
    const float* __restrict__ w_ih,    // [K, 4H, I]
    const float* __restrict__ w_hh,    // [K, 4H, H]
    const float* __restrict__ cw_t,    // [K]
    const float* __restrict__ bias_t,  // [4H]
    float* __restrict__ cstate,        // [B, H]
    float* __restrict__ out_t)         // [B, H]
{
    __shared__ float xh_s[BB][TI + 1];   // +1 pad
    __shared__ float w_s[16][TI + 1];
    __shared__ float gex[4 * BB * 4];

    const int tid  = threadIdx.x;
    const int j0   = blockIdx.x * 4;     // j0 in [0, H)
    const int b    = tid & 63;
    const int gate = tid >> 6;

    float cw[KK];
    #pragma unroll
    for (int k = 0; k < KK; ++k) cw[k] = cw_t[k];

    float acc[4] = {0.f, 0.f, 0.f, 0.f};

    for (int ci = 0; ci < II + HH; ci += TI) {
        // stage x/h tile: [64][TI], coalesced
        for (int e = tid; e < BB * TI; e += 256) {
            int bb = e >> 7, cc = e & (TI - 1);
            int c = ci + cc;
            xh_s[bb][cc] = (c < II) ? x_t[bb * II + c]
                                    : hprev[bb * HH + (c - II)];
        }
        // stage mixed weight tile: 16 rows (4 gates x 4 j) x TI cols
        const float* wbase = (ci < II) ? w_ih : w_hh;
        const int cbase    = (ci < II) ? ci : (ci - II);
        for (int e = tid; e < 16 * TI; e += 256) {
            int r = e >> 7, cc = e & (TI - 1);
            int grow = (r >> 2) * HH + j0 + (r & 3);   // gate=r>>2, d=r&3; < 4H
            size_t off = (size_t)grow * II + (size_t)(cbase + cc);
            float wm = 0.f;
            #pragma unroll
            for (int k = 0; k < KK; ++k)
                wm += cw[k] * wbase[(size_t)k * ((size_t)G4 * II) + off];
            w_s[r][cc] = wm;
        }
        __syncthreads();
        // FMA: each thread = (b, gate), 4 j-columns
        for (int c = 0; c < TI; ++c) {
            float xv = xh_s[b][c];
            #pragma unroll
            for (int d = 0; d < 4; ++d)
                acc[d] += xv * w_s[(gate << 2) + d][c];   // broadcast read
        }
        __syncthreads();
    }

    // bias + cross-gate exchange
    #pragma unroll
    for (int d = 0; d < 4; ++d) {
        acc[d] += bias_t[gate * HH + j0 + d];
        gex[gate * 256 + b * 4 + d] = acc[d];
    }
    __syncthreads();

    const int b2 = tid & 63, d2 = tid >> 6;
    float iv = gex[0 * 256 + b2 * 4 + d2];
    float fv = gex[1 * 256 + b2 * 4 + d2];
    float gv = gex[2 * 256 + b2 * 4 + d2];
    float ov = gex[3 * 256 + b2 * 4 + d2];
    float si = 1.f / (1.f + expf(-iv));
    float sf = 1.f / (1.f + expf(-fv));
    float so = 1.f / (1.f + expf(-ov));
    float tg = tanhf(gv);
    int j = j0 + d2;
    float cold = cprev[b2 * HH + j];
    float cnew = sf * cold + si * tg;
    cstate[b2 * HH + j] = cnew;
    out_t[b2 * HH + j] = so * tanhf(cnew);
}

extern "C" void kernel_launch(void* const* d_in, const int* in_sizes, int n_in,
                              void* d_out, int out_size, void* d_ws, size_t ws_size,
                              hipStream_t stream) {
    const float* x    = (const float*)d_in[0];
    const float* coef = (const float*)d_in[1];
    const float* w_ih = (const float*)d_in[2];
    const float* w_hh = (const float*)d_in[3];
    const float* b_ih = (const float*)d_in[4];
    const float* b_hh = (const float*)d_in[5];
    const float* h0   = (const float*)d_in[6];
    const float* c0   = (const float*)d_in[7];
    float* out = (float*)d_out;
    float* ws  = (float*)d_ws;

    softmax_bias_kernel<<<TT, 256, 0, stream>>>(coef, b_ih, b_hh, ws);

    for (int t = 0; t < TT; ++t) {
        const float* xt    = x + (size_t)t * BB * II;
        const float* hprev = (t == 0) ? h0 : out + (size_t)(t - 1) * BB * HH;
        const float* cprev = (t == 0) ? c0 : (ws + WS_C);
        step_kernel<<<HH / 4, 256, 0, stream>>>(
            xt, hprev, cprev, w_ih, w_hh,
            ws + WS_CW + (size_t)t * KK,
            ws + WS_BIAS + (size_t)t * G4,
            ws + WS_C,
            out + (size_t)t * BB * HH);
    }
}

// Round 4
// 3860.262 us; speedup vs baseline: 4.6623x; 4.6623x over previous
//
#include <hip/hip_runtime.h>
#include <math.h>
#include <stdint.h>

// Problem dims (fixed by reference)
#define TT 128
#define BB 64
#define II 1024
#define HH 1024
#define KK 8
#define G4 4096   // 4*H
#define MM 8192   // T*B

typedef _Float16 f16x8 __attribute__((ext_vector_type(8)));
typedef float    f32x4 __attribute__((ext_vector_type(4)));

// ---------------- workspace layout (bytes) ----------------
// cw fp32 [T][K]            @ 0         (4096 B)
// bias fp32 [T][4H]         @ 4096      (2 MB)
// c fp32 [B][H]             @ 2101248   (256 KB)
// h f16 dbuf [2][B][H]      @ 2363392   (2 x 128 KB)
// gates_x f16 [M][4H]       @ 2625536   (64 MB)
// wih f16 [K][4H][I]        @ 69734400  (64 MB)
// whh f16 [K][4H][H]        @ 136843264 (64 MB)
// x8 f16 [K][M][I]          @ 203952128 (128 MB)
#define OFF_CW    0
#define OFF_BIAS  4096
#define OFF_C     2101248
#define OFF_H0    2363392
#define OFF_H1    2494464
#define OFF_GX    2625536
#define OFF_WIH   69734400
#define OFF_WHH   136843264
#define OFF_X8    203952128
#define WS_REQ    338169856

// =========================================================
// shared by both paths: softmax(coef) + mixed bias
// =========================================================
__global__ __launch_bounds__(256) void softmax_bias_kernel(
    const float* __restrict__ coef,
    const float* __restrict__ b_ih,
    const float* __restrict__ b_hh,
    float* __restrict__ ws)
{
    int t = blockIdx.x;
    float c[KK];
    float m = -1e30f;
    #pragma unroll
    for (int k = 0; k < KK; ++k) { c[k] = coef[t*KK + k]; m = fmaxf(m, c[k]); }
    float s = 0.f;
    #pragma unroll
    for (int k = 0; k < KK; ++k) { c[k] = expf(c[k] - m); s += c[k]; }
    float inv = 1.f / s;
    #pragma unroll
    for (int k = 0; k < KK; ++k) c[k] *= inv;
    if (threadIdx.x < KK) ws[t*KK + threadIdx.x] = c[threadIdx.x];
    float* bias = ws + 1024;
    for (int g = threadIdx.x; g < G4; g += blockDim.x) {
        float acc = 0.f;
        #pragma unroll
        for (int k = 0; k < KK; ++k)
            acc += c[k] * (b_ih[k*G4 + g] + b_hh[k*G4 + g]);
        bias[t*G4 + g] = acc;
    }
}

// =========================================================
// FAST PATH
// =========================================================

// fp32 -> f16 bulk convert (count multiple of 8)
__global__ __launch_bounds__(256) void conv_f16_kernel(
    const float* __restrict__ src, _Float16* __restrict__ dst, long n8)
{
    long v = (long)blockIdx.x * 256 + threadIdx.x;
    if (v >= n8) return;
    const float* s = src + v * 8;
    f16x8 o;
    #pragma unroll
    for (int e = 0; e < 8; ++e) o[e] = (_Float16)s[e];
    *(f16x8*)(dst + v * 8) = o;
}

// x8[k][row][i] = f16(cw[t][k] * x[row][i]),  row = t*64+b
__global__ __launch_bounds__(256) void x8_kernel(
    const float* __restrict__ x, const float* __restrict__ cw,
    _Float16* __restrict__ x8)
{
    long v = (long)blockIdx.x * 256 + threadIdx.x;   // vec8 index, 8.39M total
    if (v >= (long)KK * MM * (II/8)) return;
    int k   = (int)(v / (MM * (II/8)));
    long rem = v % (MM * (II/8));
    int row = (int)(rem / (II/8));
    int i8  = (int)(rem % (II/8));
    int t   = row >> 6;
    float sc = cw[t*KK + k];
    const float* s = x + (long)row * II + i8 * 8;
    f16x8 o;
    #pragma unroll
    for (int e = 0; e < 8; ++e) o[e] = (_Float16)(sc * s[e]);
    *(f16x8*)(x8 + v * 8) = o;
}

__global__ __launch_bounds__(256) void hinit_kernel(
    const float* __restrict__ h0, _Float16* __restrict__ hws)
{
    int idx = blockIdx.x * 256 + threadIdx.x;
    hws[idx] = (_Float16)h0[idx];
}

// Phase A: gx[M=8192][N=4096] = sum over r=(k,i) of x8 * wih
// 128x128 tile, BK=64, 4 waves in 2x2 quadrants, mfma 16x16x32 f16.
#define PAD 80   // LDS row stride in f16 (64 + 16)
__global__ __launch_bounds__(256) void phaseA_gemm(
    const _Float16* __restrict__ x8,   // [8][8192][1024]
    const _Float16* __restrict__ wih,  // [8][4096][1024]
    _Float16* __restrict__ gx)         // [8192][4096]
{
    __shared__ _Float16 As[128][PAD];
    __shared__ _Float16 Bs[128][PAD];
    const int tid  = threadIdx.x;
    const int lane = tid & 63;
    const int wv   = tid >> 6;
    const int wr   = wv >> 1, wc = wv & 1;
    const int bm   = blockIdx.x & 63;     // 64 m-blocks
    const int bn   = blockIdx.x >> 6;     // 32 n-blocks
    const size_t m0 = (size_t)bm * 128, n0 = (size_t)bn * 128;

    f32x4 acc[4][4];
    #pragma unroll
    for (int i = 0; i < 4; ++i)
        #pragma unroll
        for (int j = 0; j < 4; ++j) acc[i][j] = (f32x4){0.f,0.f,0.f,0.f};

    const int srow = tid >> 3;          // 0..31 (row block per stage iter)
    const int scol = (tid & 7) * 8;     // 0..56

    for (int kt = 0; kt < 128; ++kt) {
        const int kseg = kt >> 4;
        const int i0   = (kt & 15) * 64;
        const size_t abase = (size_t)kseg * MM * II + i0;
        const size_t bbase = (size_t)kseg * G4 * II + i0;
        #pragma unroll
        for (int it = 0; it < 4; ++it) {
            int r = it * 32 + srow;
            *(f16x8*)&As[r][scol] = *(const f16x8*)(x8 + abase + (m0 + r) * II + scol);
            *(f16x8*)&Bs[r][scol] = *(const f16x8*)(wih + bbase + (n0 + r) * II + scol);
        }
        __syncthreads();
        #pragma unroll
        for (int half = 0; half < 2; ++half) {
            const int kc = half * 32 + 8 * (lane >> 4);
            f16x8 a[4], b[4];
            #pragma unroll
            for (int mf = 0; mf < 4; ++mf)
                a[mf] = *(const f16x8*)&As[wr*64 + mf*16 + (lane & 15)][kc];
            #pragma unroll
            for (int nf = 0; nf < 4; ++nf)
                b[nf] = *(const f16x8*)&Bs[wc*64 + nf*16 + (lane & 15)][kc];
            #pragma unroll
            for (int mf = 0; mf < 4; ++mf)
                #pragma unroll
                for (int nf = 0; nf < 4; ++nf)
                    acc[mf][nf] = __builtin_amdgcn_mfma_f32_16x16x32_f16(
                        a[mf], b[nf], acc[mf][nf], 0, 0, 0);
        }
        __syncthreads();
    }
    // epilogue: C row = 4*(lane>>4)+reg (+frag offsets), col = lane&15
    #pragma unroll
    for (int mf = 0; mf < 4; ++mf)
        #pragma unroll
        for (int nf = 0; nf < 4; ++nf) {
            size_t col = n0 + wc*64 + nf*16 + (lane & 15);
            size_t rw  = m0 + wr*64 + mf*16 + 4*(lane >> 4);
            #pragma unroll
            for (int r = 0; r < 4; ++r)
                gx[(rw + r) * G4 + col] = (_Float16)acc[mf][nf][r];
        }
}

// Phase B: one LSTM step. 256 blocks x 256 thr. Block owns 4 h-columns
// (16 gate rows: {g*1024 + j0 + jj}). Wave w covers k_meta {2w, 2w+1}.
__global__ __launch_bounds__(256) void stepB_kernel(
    const _Float16* __restrict__ whh,   // [8][4096][1024]
    const _Float16* __restrict__ gx_t,  // [64][4096] (row slab of gates_x)
    const float* __restrict__ cwt,      // [8]
    const float* __restrict__ bias_t,   // [4096]
    const _Float16* __restrict__ hin,   // [64][1024]
    _Float16* __restrict__ hout,        // [64][1024]
    float* __restrict__ cst,            // [64][1024]
    float* __restrict__ out_t)          // [64][1024]
{
    __shared__ _Float16 hs[BB][HH + 8];       // 132 KB, padded
    __shared__ float gpart[4][BB][17];        // 17.4 KB, padded

    const int tid  = threadIdx.x;
    const int lane = tid & 63;
    const int wv   = tid >> 6;
    const int j0   = blockIdx.x * 4;

    // stage h into LDS
    for (int idx = tid * 8; idx < BB * HH; idx += 256 * 8) {
        int row = idx >> 10, col = idx & (HH - 1);
        *(f16x8*)&hs[row][col] = *(const f16x8*)(hin + idx);
    }
    __syncthreads();

    const float cw0 = cwt[2*wv], cw1 = cwt[2*wv + 1];
    // lane's B row: q = lane&15 -> gate = q>>2, j = j0 + (q&3)
    const int q = lane & 15;
    const size_t grow = (size_t)(q >> 2) * HH + j0 + (q & 3);
    const _Float16* w0 = whh + ((size_t)(2*wv)     * G4) * II + grow * II + 8 * (lane >> 4);
    const _Float16* w1 = whh + ((size_t)(2*wv + 1) * G4) * II + grow * II + 8 * (lane >> 4);

    f32x4 acc0[4], acc1[4];
    #pragma unroll
    for (int mf = 0; mf < 4; ++mf) {
        acc0[mf] = (f32x4){0.f,0.f,0.f,0.f};
        acc1[mf] = (f32x4){0.f,0.f,0.f,0.f};
    }

    for (int kk = 0; kk < 32; ++kk) {
        const int hp = kk * 32 + 8 * (lane >> 4);
        f16x8 a[4];
        #pragma unroll
        for (int mf = 0; mf < 4; ++mf)
            a[mf] = *(const f16x8*)&hs[mf*16 + (lane & 15)][hp];
        f16x8 b0 = *(const f16x8*)(w0 + (size_t)kk * 32);
        f16x8 b1 = *(const f16x8*)(w1 + (size_t)kk * 32);
        #pragma unroll
        for (int mf = 0; mf < 4; ++mf)
            acc0[mf] = __builtin_amdgcn_mfma_f32_16x16x32_f16(a[mf], b0, acc0[mf], 0, 0, 0);
        #pragma unroll
        for (int mf = 0; mf < 4; ++mf)
            acc1[mf] = __builtin_amdgcn_mfma_f32_16x16x32_f16(a[mf], b1, acc1[mf], 0, 0, 0);
    }

    // fp32 mixture scale, write partials
    #pragma unroll
    for (int mf = 0; mf < 4; ++mf) {
        #pragma unroll
        for (int r = 0; r < 4; ++r) {
            int m = mf*16 + 4*(lane >> 4) + r;
            gpart[wv][m][q] = cw0 * acc0[mf][r] + cw1 * acc1[mf][r];
        }
    }
    __syncthreads();

    // epilogue: thread = (b, jj)
    const int b  = tid & 63;
    const int jj = tid >> 6;
    const int j  = j0 + jj;
    float gval[4];
    #pragma unroll
    for (int gate = 0; gate < 4; ++gate) {
        int qq = gate*4 + jj;
        float v = gpart[0][b][qq] + gpart[1][b][qq] + gpart[2][b][qq] + gpart[3][b][qq];
        v += (float)gx_t[(size_t)b * G4 + gate*HH + j];
        v += bias_t[gate*HH + j];
        gval[gate] = v;
    }
    float iv = 1.f / (1.f + expf(-gval[0]));
    float fv = 1.f / (1.f + expf(-gval[1]));
    float gv = tanhf(gval[2]);
    float ov = 1.f / (1.f + expf(-gval[3]));
    float c  = fv * cst[(size_t)b * HH + j] + iv * gv;
    cst[(size_t)b * HH + j] = c;
    float h  = ov * tanhf(c);
    out_t[(size_t)b * HH + j] = h;
    hout[(size_t)b * HH + j] = (_Float16)h;
}

// =========================================================
// FALLBACK PATH (R3, verified): fused per-step mixture kernel
// =========================================================
#define TI 128
__global__ __launch_bounds__(256) void step_kernel(
    const float* __restrict__ x_t, const float* __restrict__ hprev,
    const float* __restrict__ cprev, const float* __restrict__ w_ih,
    const float* __restrict__ w_hh, const float* __restrict__ cw_t,
    const float* __restrict__ bias_t, float* __restrict__ cstate,
    float* __restrict__ out_t)
{
    __shared__ float xh_s[BB][TI + 1];
    __shared__ float w_s[16][TI + 1];
    __shared__ float gex[4 * BB * 4];
    const int tid = threadIdx.x;
    const int j0 = blockIdx.x * 4;
    const int b = tid & 63;
    const int gate = tid >> 6;
    float cw[KK];
    #pragma unroll
    for (int k = 0; k < KK; ++k) cw[k] = cw_t[k];
    float acc[4] = {0.f, 0.f, 0.f, 0.f};
    for (int ci = 0; ci < II + HH; ci += TI) {
        for (int e = tid; e < BB * TI; e += 256) {
            int bb = e >> 7, cc = e & (TI - 1);
            int c = ci + cc;
            xh_s[bb][cc] = (c < II) ? x_t[bb * II + c] : hprev[bb * HH + (c - II)];
        }
        const float* wbase = (ci < II) ? w_ih : w_hh;
        const int cbase = (ci < II) ? ci : (ci - II);
        for (int e = tid; e < 16 * TI; e += 256) {
            int r = e >> 7, cc = e & (TI - 1);
            int grw = (r >> 2) * HH + j0 + (r & 3);
            size_t off = (size_t)grw * II + (size_t)(cbase + cc);
            float wm = 0.f;
            #pragma unroll
            for (int k = 0; k < KK; ++k)
                wm += cw[k] * wbase[(size_t)k * ((size_t)G4 * II) + off];
            w_s[r][cc] = wm;
        }
        __syncthreads();
        for (int c = 0; c < TI; ++c) {
            float xv = xh_s[b][c];
            #pragma unroll
            for (int d = 0; d < 4; ++d)
                acc[d] += xv * w_s[(gate << 2) + d][c];
        }
        __syncthreads();
    }
    #pragma unroll
    for (int d = 0; d < 4; ++d) {
        acc[d] += bias_t[gate * HH + j0 + d];
        gex[gate * 256 + b * 4 + d] = acc[d];
    }
    __syncthreads();
    const int b2 = tid & 63, d2 = tid >> 6;
    float iv = gex[0 * 256 + b2 * 4 + d2];
    float fv = gex[1 * 256 + b2 * 4 + d2];
    float gv = gex[2 * 256 + b2 * 4 + d2];
    float ov = gex[3 * 256 + b2 * 4 + d2];
    float si = 1.f / (1.f + expf(-iv));
    float sf = 1.f / (1.f + expf(-fv));
    float so = 1.f / (1.f + expf(-ov));
    float tg = tanhf(gv);
    int j = j0 + d2;
    float cold = cprev[b2 * HH + j];
    float cnew = sf * cold + si * tg;
    cstate[b2 * HH + j] = cnew;
    out_t[b2 * HH + j] = so * tanhf(cnew);
}

// =========================================================
extern "C" void kernel_launch(void* const* d_in, const int* in_sizes, int n_in,
                              void* d_out, int out_size, void* d_ws, size_t ws_size,
                              hipStream_t stream) {
    const float* x    = (const float*)d_in[0];
    const float* coef = (const float*)d_in[1];
    const float* w_ih = (const float*)d_in[2];
    const float* w_hh = (const float*)d_in[3];
    const float* b_ih = (const float*)d_in[4];
    const float* b_hh = (const float*)d_in[5];
    const float* h0   = (const float*)d_in[6];
    const float* c0   = (const float*)d_in[7];
    float* out = (float*)d_out;
    char* ws   = (char*)d_ws;
    float* cw_f   = (float*)(ws + OFF_CW);
    float* bias_f = (float*)(ws + OFF_BIAS);
    float* c_f    = (float*)(ws + OFF_C);

    softmax_bias_kernel<<<TT, 256, 0, stream>>>(coef, b_ih, b_hh, (float*)ws);

    if (ws_size >= (size_t)WS_REQ) {
        _Float16* hws[2] = { (_Float16*)(ws + OFF_H0), (_Float16*)(ws + OFF_H1) };
        _Float16* gx   = (_Float16*)(ws + OFF_GX);
        _Float16* wihf = (_Float16*)(ws + OFF_WIH);
        _Float16* whhf = (_Float16*)(ws + OFF_WHH);
        _Float16* x8   = (_Float16*)(ws + OFF_X8);

        conv_f16_kernel<<<16384, 256, 0, stream>>>(w_ih, wihf, (long)KK*G4*II/8);
        conv_f16_kernel<<<16384, 256, 0, stream>>>(w_hh, whhf, (long)KK*G4*II/8);
        x8_kernel<<<32768, 256, 0, stream>>>(x, cw_f, x8);
        hinit_kernel<<<256, 256, 0, stream>>>(h0, hws[0]);
        hipMemcpyAsync(c_f, c0, (size_t)BB*HH*4, hipMemcpyDeviceToDevice, stream);

        phaseA_gemm<<<2048, 256, 0, stream>>>(x8, wihf, gx);

        for (int t = 0; t < TT; ++t) {
            stepB_kernel<<<256, 256, 0, stream>>>(
                whhf,
                gx + (size_t)t * BB * G4,
                cw_f + t * KK,
                bias_f + (size_t)t * G4,
                hws[t & 1], hws[1 - (t & 1)],
                c_f,
                out + (size_t)t * BB * HH);
        }
    } else {
        // fallback: verified R3 path (ws layout compatible)
        for (int t = 0; t < TT; ++t) {
            const float* xt    = x + (size_t)t * BB * II;
            const float* hprev = (t == 0) ? h0 : out + (size_t)(t - 1) * BB * HH;
            const float* cprev = (t == 0) ? c0 : c_f;
            step_kernel<<<HH / 4, 256, 0, stream>>>(
                xt, hprev, cprev, w_ih, w_hh,
                cw_f + (size_t)t * KK,
                bias_f + (size_t)t * G4,
                c_f,
                out + (size_t)t * BB * HH);
        }
    }
}

// Round 5
// 3800.709 us; speedup vs baseline: 4.7354x; 1.0157x over previous
//
#include <hip/hip_runtime.h>
#include <math.h>
#include <stdint.h>

// Problem dims (fixed by reference)
#define TT 128
#define BB 64
#define II 1024
#define HH 1024
#define KK 8
#define G4 4096   // 4*H
#define MM 8192   // T*B

typedef _Float16 f16x8 __attribute__((ext_vector_type(8)));
typedef float    f32x4 __attribute__((ext_vector_type(4)));

// ---------------- workspace layout (bytes) ----------------
#define OFF_CW    0           // cw fp32 [T][K]
#define OFF_BIAS  4096        // bias fp32 [T][4H]
#define OFF_C     2101248     // c fp32 [B][H]
#define OFF_H0    2363392     // h f16 dbuf 0
#define OFF_H1    2494464     // h f16 dbuf 1
#define OFF_GX    2625536     // gates_x f16 [M][4H]
#define OFF_WIH   69734400    // wih f16 [K][4H][I]
#define OFF_WHHP  136843264   // whh PACKED f16 [256][8][32][64][8]
#define OFF_X8    203952128   // x8 f16 [K][M][I]
#define WS_REQ    338169856

// =========================================================
// softmax(coef) + mixed bias (both paths)
// =========================================================
__global__ __launch_bounds__(256) void softmax_bias_kernel(
    const float* __restrict__ coef,
    const float* __restrict__ b_ih,
    const float* __restrict__ b_hh,
    float* __restrict__ ws)
{
    int t = blockIdx.x;
    float c[KK];
    float m = -1e30f;
    #pragma unroll
    for (int k = 0; k < KK; ++k) { c[k] = coef[t*KK + k]; m = fmaxf(m, c[k]); }
    float s = 0.f;
    #pragma unroll
    for (int k = 0; k < KK; ++k) { c[k] = expf(c[k] - m); s += c[k]; }
    float inv = 1.f / s;
    #pragma unroll
    for (int k = 0; k < KK; ++k) c[k] *= inv;
    if (threadIdx.x < KK) ws[t*KK + threadIdx.x] = c[threadIdx.x];
    float* bias = ws + 1024;
    for (int g = threadIdx.x; g < G4; g += blockDim.x) {
        float acc = 0.f;
        #pragma unroll
        for (int k = 0; k < KK; ++k)
            acc += c[k] * (b_ih[k*G4 + g] + b_hh[k*G4 + g]);
        bias[t*G4 + g] = acc;
    }
}

// =========================================================
// FAST PATH setup kernels
// =========================================================
__global__ __launch_bounds__(256) void conv_f16_kernel(
    const float* __restrict__ src, _Float16* __restrict__ dst, long n8)
{
    long v = (long)blockIdx.x * 256 + threadIdx.x;
    if (v >= n8) return;
    const float* s = src + v * 8;
    f16x8 o;
    #pragma unroll
    for (int e = 0; e < 8; ++e) o[e] = (_Float16)s[e];
    *(f16x8*)(dst + v * 8) = o;
}

// Pack whh (fp32) into stepB2 consumption order:
// vec8 index v = ((bj*8 + k)*32 + kk)*64 + l
// value = f16(w_hh[k][grow][kk*32 + 8*(l>>4) .. +8]),
//   q = l&15, grow = (q>>2)*1024 + bj*4 + (q&3)
__global__ __launch_bounds__(256) void pack_whh_kernel(
    const float* __restrict__ w_hh, _Float16* __restrict__ whhp)
{
    long v = (long)blockIdx.x * 256 + threadIdx.x;   // < 4194304
    int l  = (int)(v & 63);
    long r1 = v >> 6;
    int kk = (int)(r1 & 31);
    long c = r1 >> 5;
    int k  = (int)(c & 7);
    int bj = (int)(c >> 3);
    int q  = l & 15;
    int grow = (q >> 2) * HH + bj * 4 + (q & 3);
    int col  = kk * 32 + 8 * (l >> 4);
    const float* s = w_hh + ((size_t)k * G4 + grow) * II + col;
    f16x8 o;
    #pragma unroll
    for (int e = 0; e < 8; ++e) o[e] = (_Float16)s[e];
    *(f16x8*)(whhp + v * 8) = o;
}

// x8[k][row][i] = f16(cw[t][k] * x[row][i]),  row = t*64+b
__global__ __launch_bounds__(256) void x8_kernel(
    const float* __restrict__ x, const float* __restrict__ cw,
    _Float16* __restrict__ x8)
{
    long v = (long)blockIdx.x * 256 + threadIdx.x;
    if (v >= (long)KK * MM * (II/8)) return;
    int k   = (int)(v / (MM * (II/8)));
    long rem = v % (MM * (II/8));
    int row = (int)(rem / (II/8));
    int i8  = (int)(rem % (II/8));
    int t   = row >> 6;
    float sc = cw[t*KK + k];
    const float* s = x + (long)row * II + i8 * 8;
    f16x8 o;
    #pragma unroll
    for (int e = 0; e < 8; ++e) o[e] = (_Float16)(sc * s[e]);
    *(f16x8*)(x8 + v * 8) = o;
}

__global__ __launch_bounds__(256) void hinit_kernel(
    const float* __restrict__ h0, _Float16* __restrict__ hws)
{
    int idx = blockIdx.x * 256 + threadIdx.x;
    hws[idx] = (_Float16)h0[idx];
}

// =========================================================
// Phase A GEMM (unchanged from R4)
// =========================================================
#define PAD 80
__global__ __launch_bounds__(256) void phaseA_gemm(
    const _Float16* __restrict__ x8,
    const _Float16* __restrict__ wih,
    _Float16* __restrict__ gx)
{
    __shared__ _Float16 As[128][PAD];
    __shared__ _Float16 Bs[128][PAD];
    const int tid  = threadIdx.x;
    const int lane = tid & 63;
    const int wv   = tid >> 6;
    const int wr   = wv >> 1, wc = wv & 1;
    const int bm   = blockIdx.x & 63;
    const int bn   = blockIdx.x >> 6;
    const size_t m0 = (size_t)bm * 128, n0 = (size_t)bn * 128;

    f32x4 acc[4][4];
    #pragma unroll
    for (int i = 0; i < 4; ++i)
        #pragma unroll
        for (int j = 0; j < 4; ++j) acc[i][j] = (f32x4){0.f,0.f,0.f,0.f};

    const int srow = tid >> 3;
    const int scol = (tid & 7) * 8;

    for (int kt = 0; kt < 128; ++kt) {
        const int kseg = kt >> 4;
        const int i0   = (kt & 15) * 64;
        const size_t abase = (size_t)kseg * MM * II + i0;
        const size_t bbase = (size_t)kseg * G4 * II + i0;
        #pragma unroll
        for (int it = 0; it < 4; ++it) {
            int r = it * 32 + srow;
            *(f16x8*)&As[r][scol] = *(const f16x8*)(x8 + abase + (m0 + r) * II + scol);
            *(f16x8*)&Bs[r][scol] = *(const f16x8*)(wih + bbase + (n0 + r) * II + scol);
        }
        __syncthreads();
        #pragma unroll
        for (int half = 0; half < 2; ++half) {
            const int kc = half * 32 + 8 * (lane >> 4);
            f16x8 a[4], b[4];
            #pragma unroll
            for (int mf = 0; mf < 4; ++mf)
                a[mf] = *(const f16x8*)&As[wr*64 + mf*16 + (lane & 15)][kc];
            #pragma unroll
            for (int nf = 0; nf < 4; ++nf)
                b[nf] = *(const f16x8*)&Bs[wc*64 + nf*16 + (lane & 15)][kc];
            #pragma unroll
            for (int mf = 0; mf < 4; ++mf)
                #pragma unroll
                for (int nf = 0; nf < 4; ++nf)
                    acc[mf][nf] = __builtin_amdgcn_mfma_f32_16x16x32_f16(
                        a[mf], b[nf], acc[mf][nf], 0, 0, 0);
        }
        __syncthreads();
    }
    #pragma unroll
    for (int mf = 0; mf < 4; ++mf)
        #pragma unroll
        for (int nf = 0; nf < 4; ++nf) {
            size_t col = n0 + wc*64 + nf*16 + (lane & 15);
            size_t rw  = m0 + wr*64 + mf*16 + 4*(lane >> 4);
            #pragma unroll
            for (int r = 0; r < 4; ++r)
                gx[(rw + r) * G4 + col] = (_Float16)acc[mf][nf][r];
        }
}

// =========================================================
// Phase B v2: packed-coalesced weight stream + 8-deep prefetch
// =========================================================
__global__ __launch_bounds__(256) void stepB2_kernel(
    const _Float16* __restrict__ whhp,  // packed [256][8][32][64][8]
    const _Float16* __restrict__ gx_t,  // [64][4096]
    const float* __restrict__ cwt,      // [8]
    const float* __restrict__ bias_t,   // [4096]
    const _Float16* __restrict__ hin,   // [64][1024]
    _Float16* __restrict__ hout,        // [64][1024]
    float* __restrict__ cst,            // [64][1024]
    float* __restrict__ out_t)          // [64][1024]
{
    __shared__ _Float16 hs[BB][HH + 8];
    __shared__ float gpart[4][BB][17];

    const int tid  = threadIdx.x;
    const int lane = tid & 63;
    const int wv   = tid >> 6;
    const int bj   = blockIdx.x;
    const int j0   = bj * 4;

    // packed weight streams for this (block, wave): two contiguous 32 KB runs
    const _Float16* w0 = whhp + (((size_t)bj * 8 + 2*wv    ) * 32) * 512;
    const _Float16* w1 = whhp + (((size_t)bj * 8 + 2*wv + 1) * 32) * 512;

    // prefetch first 8 kk iterations of B (independent of LDS staging)
    f16x8 pb0[8], pb1[8];
    #pragma unroll
    for (int u = 0; u < 8; ++u) {
        pb0[u] = *(const f16x8*)(w0 + (size_t)u * 512 + lane * 8);
        pb1[u] = *(const f16x8*)(w1 + (size_t)u * 512 + lane * 8);
    }

    // stage h into LDS (reg-staged, verified path)
    for (int idx = tid * 8; idx < BB * HH; idx += 256 * 8) {
        int row = idx >> 10, col = idx & (HH - 1);
        *(f16x8*)&hs[row][col] = *(const f16x8*)(hin + idx);
    }
    __syncthreads();

    const float cw0 = cwt[2*wv], cw1 = cwt[2*wv + 1];
    const int q = lane & 15;

    f32x4 acc0[4], acc1[4];
    #pragma unroll
    for (int mf = 0; mf < 4; ++mf) {
        acc0[mf] = (f32x4){0.f,0.f,0.f,0.f};
        acc1[mf] = (f32x4){0.f,0.f,0.f,0.f};
    }

    for (int g = 0; g < 4; ++g) {          // kk = g*8 + u
        #pragma unroll
        for (int u = 0; u < 8; ++u) {
            const int kk = g * 8 + u;
            const int hp = kk * 32 + 8 * (lane >> 4);
            f16x8 a[4];
            #pragma unroll
            for (int mf = 0; mf < 4; ++mf)
                a[mf] = *(const f16x8*)&hs[mf*16 + (lane & 15)][hp];
            #pragma unroll
            for (int mf = 0; mf < 4; ++mf)
                acc0[mf] = __builtin_amdgcn_mfma_f32_16x16x32_f16(a[mf], pb0[u], acc0[mf], 0, 0, 0);
            #pragma unroll
            for (int mf = 0; mf < 4; ++mf)
                acc1[mf] = __builtin_amdgcn_mfma_f32_16x16x32_f16(a[mf], pb1[u], acc1[mf], 0, 0, 0);
            if (g < 3) {   // uniform branch; reload slot for kk+8
                pb0[u] = *(const f16x8*)(w0 + (size_t)(kk + 8) * 512 + lane * 8);
                pb1[u] = *(const f16x8*)(w1 + (size_t)(kk + 8) * 512 + lane * 8);
            }
        }
    }

    // fp32 mixture scale, write partials
    #pragma unroll
    for (int mf = 0; mf < 4; ++mf) {
        #pragma unroll
        for (int r = 0; r < 4; ++r) {
            int m = mf*16 + 4*(lane >> 4) + r;
            gpart[wv][m][q] = cw0 * acc0[mf][r] + cw1 * acc1[mf][r];
        }
    }
    __syncthreads();

    // epilogue: thread = (b, jj)
    const int b  = tid & 63;
    const int jj = tid >> 6;
    const int j  = j0 + jj;
    float gval[4];
    #pragma unroll
    for (int gate = 0; gate < 4; ++gate) {
        int qq = gate*4 + jj;
        float v = gpart[0][b][qq] + gpart[1][b][qq] + gpart[2][b][qq] + gpart[3][b][qq];
        v += (float)gx_t[(size_t)b * G4 + gate*HH + j];
        v += bias_t[gate*HH + j];
        gval[gate] = v;
    }
    float iv = 1.f / (1.f + expf(-gval[0]));
    float fv = 1.f / (1.f + expf(-gval[1]));
    float gv = tanhf(gval[2]);
    float ov = 1.f / (1.f + expf(-gval[3]));
    float c  = fv * cst[(size_t)b * HH + j] + iv * gv;
    cst[(size_t)b * HH + j] = c;
    float h  = ov * tanhf(c);
    out_t[(size_t)b * HH + j] = h;
    hout[(size_t)b * HH + j] = (_Float16)h;
}

// =========================================================
// FALLBACK PATH (R3, verified)
// =========================================================
#define TI 128
__global__ __launch_bounds__(256) void step_kernel(
    const float* __restrict__ x_t, const float* __restrict__ hprev,
    const float* __restrict__ cprev, const float* __restrict__ w_ih,
    const float* __restrict__ w_hh, const float* __restrict__ cw_t,
    const float* __restrict__ bias_t, float* __restrict__ cstate,
    float* __restrict__ out_t)
{
    __shared__ float xh_s[BB][TI + 1];
    __shared__ float w_s[16][TI + 1];
    __shared__ float gex[4 * BB * 4];
    const int tid = threadIdx.x;
    const int j0 = blockIdx.x * 4;
    const int b = tid & 63;
    const int gate = tid >> 6;
    float cw[KK];
    #pragma unroll
    for (int k = 0; k < KK; ++k) cw[k] = cw_t[k];
    float acc[4] = {0.f, 0.f, 0.f, 0.f};
    for (int ci = 0; ci < II + HH; ci += TI) {
        for (int e = tid; e < BB * TI; e += 256) {
            int bb = e >> 7, cc = e & (TI - 1);
            int c = ci + cc;
            xh_s[bb][cc] = (c < II) ? x_t[bb * II + c] : hprev[bb * HH + (c - II)];
        }
        const float* wbase = (ci < II) ? w_ih : w_hh;
        const int cbase = (ci < II) ? ci : (ci - II);
        for (int e = tid; e < 16 * TI; e += 256) {
            int r = e >> 7, cc = e & (TI - 1);
            int grw = (r >> 2) * HH + j0 + (r & 3);
            size_t off = (size_t)grw * II + (size_t)(cbase + cc);
            float wm = 0.f;
            #pragma unroll
            for (int k = 0; k < KK; ++k)
                wm += cw[k] * wbase[(size_t)k * ((size_t)G4 * II) + off];
            w_s[r][cc] = wm;
        }
        __syncthreads();
        for (int c = 0; c < TI; ++c) {
            float xv = xh_s[b][c];
            #pragma unroll
            for (int d = 0; d < 4; ++d)
                acc[d] += xv * w_s[(gate << 2) + d][c];
        }
        __syncthreads();
    }
    #pragma unroll
    for (int d = 0; d < 4; ++d) {
        acc[d] += bias_t[gate * HH + j0 + d];
        gex[gate * 256 + b * 4 + d] = acc[d];
    }
    __syncthreads();
    const int b2 = tid & 63, d2 = tid >> 6;
    float iv = gex[0 * 256 + b2 * 4 + d2];
    float fv = gex[1 * 256 + b2 * 4 + d2];
    float gv = gex[2 * 256 + b2 * 4 + d2];
    float ov = gex[3 * 256 + b2 * 4 + d2];
    float si = 1.f / (1.f + expf(-iv));
    float sf = 1.f / (1.f + expf(-fv));
    float so = 1.f / (1.f + expf(-ov));
    float tg = tanhf(gv);
    int j = j0 + d2;
    float cold = cprev[b2 * HH + j];
    float cnew = sf * cold + si * tg;
    cstate[b2 * HH + j] = cnew;
    out_t[b2 * HH + j] = so * tanhf(cnew);
}

// =========================================================
extern "C" void kernel_launch(void* const* d_in, const int* in_sizes, int n_in,
                              void* d_out, int out_size, void* d_ws, size_t ws_size,
                              hipStream_t stream) {
    const float* x    = (const float*)d_in[0];
    const float* coef = (const float*)d_in[1];
    const float* w_ih = (const float*)d_in[2];
    const float* w_hh = (const float*)d_in[3];
    const float* b_ih = (const float*)d_in[4];
    const float* b_hh = (const float*)d_in[5];
    const float* h0   = (const float*)d_in[6];
    const float* c0   = (const float*)d_in[7];
    float* out = (float*)d_out;
    char* ws   = (char*)d_ws;
    float* cw_f   = (float*)(ws + OFF_CW);
    float* bias_f = (float*)(ws + OFF_BIAS);
    float* c_f    = (float*)(ws + OFF_C);

    softmax_bias_kernel<<<TT, 256, 0, stream>>>(coef, b_ih, b_hh, (float*)ws);

    if (ws_size >= (size_t)WS_REQ) {
        _Float16* hws[2] = { (_Float16*)(ws + OFF_H0), (_Float16*)(ws + OFF_H1) };
        _Float16* gx   = (_Float16*)(ws + OFF_GX);
        _Float16* wihf = (_Float16*)(ws + OFF_WIH);
        _Float16* whhp = (_Float16*)(ws + OFF_WHHP);
        _Float16* x8   = (_Float16*)(ws + OFF_X8);

        conv_f16_kernel<<<16384, 256, 0, stream>>>(w_ih, wihf, (long)KK*G4*II/8);
        pack_whh_kernel<<<16384, 256, 0, stream>>>(w_hh, whhp);
        x8_kernel<<<32768, 256, 0, stream>>>(x, cw_f, x8);
        hinit_kernel<<<256, 256, 0, stream>>>(h0, hws[0]);
        hipMemcpyAsync(c_f, c0, (size_t)BB*HH*4, hipMemcpyDeviceToDevice, stream);

        phaseA_gemm<<<2048, 256, 0, stream>>>(x8, wihf, gx);

        for (int t = 0; t < TT; ++t) {
            stepB2_kernel<<<256, 256, 0, stream>>>(
                whhp,
                gx + (size_t)t * BB * G4,
                cw_f + t * KK,
                bias_f + (size_t)t * G4,
                hws[t & 1], hws[1 - (t & 1)],
                c_f,
                out + (size_t)t * BB * HH);
        }
    } else {
        for (int t = 0; t < TT; ++t) {
            const float* xt    = x + (size_t)t * BB * II;
            const float* hprev = (t == 0) ? h0 : out + (size_t)(t - 1) * BB * HH;
            const float* cprev = (t == 0) ? c0 : c_f;
            step_kernel<<<HH / 4, 256, 0, stream>>>(
                xt, hprev, cprev, w_ih, w_hh,
                cw_f + (size_t)t * KK,
                bias_f + (size_t)t * G4,
                c_f,
                out + (size_t)t * BB * HH);
        }
    }
}